// Round 7
// baseline (66.819 us; speedup 1.0000x reference)
//
#include <hip/hip_runtime.h>
#include <math.h>

namespace {

constexpr int   L     = 3750;
constexpr int   NPAIR = L / 2;      // 1875 float2 per row
constexpr int   CH    = 60;         // elems per lane (15 quads, conflict-free stride)
constexpr int   PADL  = 64 * CH;    // 3840
constexpr int   TAIL  = NPAIR - 29 * 64;      // 19
constexpr int   ZPAIR = PADL / 2 - NPAIR;     // 45 zero pairs
constexpr float EPS   = 1e-5f;

__device__ __forceinline__ float frcp(float x)  { return __builtin_amdgcn_rcpf(x); }
__device__ __forceinline__ float fsqrt(float x) { return __builtin_amdgcn_sqrtf(x); }

__global__ __launch_bounds__(64)
void preproc_kernel(const float* __restrict__ in, float* __restrict__ out) {
    // one row per wave; linear LDS, no swizzle (stride-15-quad access patterns)
    __shared__ __align__(16) float sp[PADL];

    const int lane = threadIdx.x;            // 0..63, single wave
    const size_t rowoff = (size_t)blockIdx.x * (size_t)L;
    const float* rin  = in  + rowoff;
    float*       rout = out + rowoff;

    // ---- phase 1: coalesced load -> LDS (batched: 29+tail loads, then writes) ----
    {
        const float2* g = reinterpret_cast<const float2*>(rin);
        float2 v[30];
        #pragma unroll
        for (int k = 0; k < 29; ++k) v[k] = g[64 * k + lane];
        if (lane < TAIL) v[29] = g[64 * 29 + lane];
        float2* sp2 = reinterpret_cast<float2*>(sp);
        #pragma unroll
        for (int k = 0; k < 29; ++k) sp2[64 * k + lane] = v[k];
        if (lane < TAIL) sp2[64 * 29 + lane] = v[29];
        if (lane < ZPAIR) {                  // zero-pad [3750, 3840)
            float2 z; z.x = 0.f; z.y = 0.f;
            sp2[NPAIR + lane] = z;
        }
    }
    __syncthreads();                         // S1

    // ---- phase 2: chunk -> registers (15 x b128, own region) ----
    float y[CH];
    {
        const float4* q4 = reinterpret_cast<const float4*>(sp);
        #pragma unroll
        for (int h = 0; h < 15; ++h) {
            const float4 v = q4[15 * lane + h];
            y[4*h+0] = v.x; y[4*h+1] = v.y; y[4*h+2] = v.z; y[4*h+3] = v.w;
        }
    }

    // ---- sums: scan(sum y), total(sum y^2) ----
    float cy = 0.f, cy2 = 0.f;
    #pragma unroll
    for (int j = 0; j < CH; ++j) { cy += y[j]; cy2 = fmaf(y[j], y[j], cy2); }
    float iy = cy;
    #pragma unroll
    for (int d = 1; d < 64; d <<= 1) {
        const float u = __shfl_up(iy, (unsigned)d, 64);
        if (lane >= d) iy += u;
    }
    float t2 = cy2;
    #pragma unroll
    for (int d = 1; d < 64; d <<= 1) t2 += __shfl_xor(t2, d, 64);
    const float totY = __shfl(iy, 63, 64);
    const float mean = totY * (1.f / (float)L);
    const float var  = (t2 - totY * mean) * (1.f / (float)(L - 1));
    const float s    = fsqrt(var) + EPS;     // std + eps
    const float epsS = EPS * s;              // exact algebra: r = u/(sqrt(MVu2)+eps*s)

    // ---- phase 3: exclusive y-prefix -> sp (own region, 15 x b128) ----
    {
        float run = iy - cy;
        float4* q4 = reinterpret_cast<float4*>(sp);
        #pragma unroll
        for (int h = 0; h < 15; ++h) {
            float4 w;
            w.x = run; run += y[4*h+0];
            w.y = run; run += y[4*h+1];
            w.z = run; run += y[4*h+2];
            w.w = run; run += y[4*h+3];
            q4[15 * lane + h] = w;
        }
    }
    __syncthreads();                         // S2: y-prefix visible

    // ---- phase 4: u = y - MA(y) (interior; mean term at clamped edges) ----
    const float inv251 = 1.f / 251.f;
    #pragma unroll
    for (int m = 0; m < 3; ++m) {
        const int i0 = 60 * lane + 20 * m;
        if (i0 >= 125 && i0 <= 3605) {       // untruncated windows for all 20 j
            const float4* q4 = reinterpret_cast<const float4*>(sp);
            const int qlo = 15 * lane + 5 * m - 32;   // float i0-125 = quad qlo, off 3
            const int qhi = 15 * lane + 5 * m + 31;   // float i0+126 = quad qhi, off 2
            float a[24], b[24];
            #pragma unroll
            for (int h = 0; h < 6; ++h) {
                const float4 v = q4[qlo + h];
                a[4*h]=v.x; a[4*h+1]=v.y; a[4*h+2]=v.z; a[4*h+3]=v.w;
            }
            #pragma unroll
            for (int h = 0; h < 6; ++h) {
                const float4 v = q4[qhi + h];
                b[4*h]=v.x; b[4*h+1]=v.y; b[4*h+2]=v.z; b[4*h+3]=v.w;
            }
            #pragma unroll
            for (int j = 0; j < 20; ++j) {
                const float sumY = b[2 + j] - a[3 + j];
                y[20*m + j] = fmaf(sumY, -inv251, y[20*m + j]);
            }
        } else {                             // clamped (lanes 0-2, 60-63 + pad)
            #pragma unroll
            for (int j = 0; j < 20; ++j) {
                const int i  = i0 + j;
                const int lo = (i > 125) ? i - 125 : 0;
                const int hi = (i + 126 < L) ? i + 126 : L;
                const float sumY = sp[hi] - sp[lo];
                const float cnt  = (float)(hi - lo);
                y[20*m + j] = y[20*m + j] - mean - (sumY - cnt * mean) * inv251;
            }
        }
    }

    // ---- u^2 scan ----
    float cu = 0.f;
    #pragma unroll
    for (int j = 0; j < CH; ++j) cu = fmaf(y[j], y[j], cu);
    float iu = cu;
    #pragma unroll
    for (int d = 1; d < 64; d <<= 1) {
        const float t = __shfl_up(iu, (unsigned)d, 64);
        if (lane >= d) iu += t;
    }
    __syncthreads();                         // S3: all MA reads done (WAR)

    // ---- phase 5: exclusive u^2-prefix -> sp ----
    {
        float run = iu - cu;
        float4* q4 = reinterpret_cast<float4*>(sp);
        #pragma unroll
        for (int h = 0; h < 15; ++h) {
            float4 w;
            w.x = run; run = fmaf(y[4*h+0], y[4*h+0], run);
            w.y = run; run = fmaf(y[4*h+1], y[4*h+1], run);
            w.z = run; run = fmaf(y[4*h+2], y[4*h+2], run);
            w.w = run; run = fmaf(y[4*h+3], y[4*h+3], run);
            q4[15 * lane + h] = w;
        }
    }
    __syncthreads();                         // S4: u^2-prefix visible

    // ---- phase 6: r = u / (sqrt(MV)+eps*s), in regs ----
    const float inv501 = 1.f / 501.f;
    #pragma unroll
    for (int m = 0; m < 3; ++m) {
        const int i0 = 60 * lane + 20 * m;
        if (i0 >= 250 && i0 <= 3480) {
            const float4* q4 = reinterpret_cast<const float4*>(sp);
            const int qlo = 15 * lane + 5 * m - 63;   // float i0-250 = quad qlo, off 2
            const int qhi = 15 * lane + 5 * m + 62;   // float i0+251 = quad qhi, off 3
            float a[24], b[24];
            #pragma unroll
            for (int h = 0; h < 6; ++h) {
                const float4 v = q4[qlo + h];
                a[4*h]=v.x; a[4*h+1]=v.y; a[4*h+2]=v.z; a[4*h+3]=v.w;
            }
            #pragma unroll
            for (int h = 0; h < 6; ++h) {
                const float4 v = q4[qhi + h];
                b[4*h]=v.x; b[4*h+1]=v.y; b[4*h+2]=v.z; b[4*h+3]=v.w;
            }
            #pragma unroll
            for (int j = 0; j < 20; ++j) {
                float W = (b[3 + j] - a[2 + j]) * inv501;
                W = fmaxf(W, 0.f);
                y[20*m + j] = y[20*m + j] * frcp(fsqrt(W) + epsS);
            }
        } else {
            #pragma unroll
            for (int j = 0; j < 20; ++j) {
                const int i  = i0 + j;
                const int lo = (i > 250) ? i - 250 : 0;
                const int hi = (i + 251 < L) ? i + 251 : L;
                float W = (sp[hi] - sp[lo]) * inv501;
                W = fmaxf(W, 0.f);
                y[20*m + j] = y[20*m + j] * frcp(fsqrt(W) + epsS);
            }
        }
    }
    __syncthreads();                         // S5: all MV reads done (WAR)

    // ---- phase 7: r -> LDS (own region) ----
    {
        float4* q4 = reinterpret_cast<float4*>(sp);
        #pragma unroll
        for (int h = 0; h < 15; ++h) {
            float4 v;
            v.x = y[4*h+0]; v.y = y[4*h+1]; v.z = y[4*h+2]; v.w = y[4*h+3];
            q4[15 * lane + h] = v;
        }
    }
    __syncthreads();                         // S6: results staged

    // ---- phase 8: coalesced store (batched reads, then stores) ----
    {
        const float2* sp2 = reinterpret_cast<const float2*>(sp);
        float2* g = reinterpret_cast<float2*>(rout);
        float2 v[30];
        #pragma unroll
        for (int k = 0; k < 29; ++k) v[k] = sp2[64 * k + lane];
        if (lane < TAIL) v[29] = sp2[64 * 29 + lane];
        #pragma unroll
        for (int k = 0; k < 29; ++k) g[64 * k + lane] = v[k];
        if (lane < TAIL) g[64 * 29 + lane] = v[29];
    }
}

}  // namespace

extern "C" void kernel_launch(void* const* d_in, const int* in_sizes, int n_in,
                              void* d_out, int out_size, void* d_ws, size_t ws_size,
                              hipStream_t stream) {
    const float* x = (const float*)d_in[0];
    float* out = (float*)d_out;
    const int rows = in_sizes[0] / L;   // 8192
    preproc_kernel<<<rows, 64, 0, stream>>>(x, out);
}

// Round 8
// 48.327 us; speedup vs baseline: 1.3827x; 1.3827x over previous
//
#include <hip/hip_runtime.h>
#include <math.h>

namespace {

constexpr int L      = 3750;
constexpr int NPAIR  = L / 2;     // 1875 float2 per row
constexpr int BLK    = 256;
constexpr int CH     = 15;        // chunk per thread (odd stride => conflict-free)
constexpr int NCHUNK = L / CH;    // 250 active chunk threads
constexpr float EPS  = 1e-5f;

__device__ __forceinline__ float frcp(float x)  { return __builtin_amdgcn_rcpf(x); }
__device__ __forceinline__ float fsqrt(float x) { return __builtin_amdgcn_sqrtf(x); }

__global__ __launch_bounds__(BLK, 8)
void preproc_kernel(const float* __restrict__ in, float* __restrict__ out) {
    // ONE row-sized LDS array, reused: staging -> y-prefix -> u^2-prefix -> result
    __shared__ __align__(16) float sp[L + 2];
    __shared__ float sred[8];     // wave partials: [0:4) sum, [4:8) sumsq

    const int tid  = threadIdx.x;
    const int lane = tid & 63;
    const int wave = tid >> 6;
    const size_t rowoff = (size_t)blockIdx.x * (size_t)L;
    const float* rin  = in  + rowoff;
    float*       rout = out + rowoff;

    const bool active = (tid < NCHUNK);
    const int  base   = tid * CH;

    // ---- 1. coalesced load of the row into sp[0..L) ----
    {
        const float2* rin2 = reinterpret_cast<const float2*>(rin);
        float2* sp2 = reinterpret_cast<float2*>(sp);
        for (int i = tid; i < NPAIR; i += BLK) sp2[i] = rin2[i];
    }
    __syncthreads();                          // B1

    // ---- 2. chunk -> registers; block reduce (sum via scan, sumsq via xor) ----
    float y[CH];
    float cy = 0.f, cy2 = 0.f;
    if (active) {
        #pragma unroll
        for (int j = 0; j < CH; ++j) {
            const float v = sp[base + j];
            y[j] = v;
            cy  += v;
            cy2  = fmaf(v, v, cy2);
        }
    } else {
        #pragma unroll
        for (int j = 0; j < CH; ++j) y[j] = 0.f;
    }
    float iy = cy;
    #pragma unroll
    for (int d = 1; d < 64; d <<= 1) {
        const float u = __shfl_up(iy, (unsigned)d, 64);
        if (lane >= d) iy += u;
    }
    float t2 = cy2;
    #pragma unroll
    for (int d = 1; d < 64; d <<= 1) t2 += __shfl_xor(t2, d, 64);
    if (lane == 63) { sred[wave] = iy; sred[4 + wave] = t2; }
    __syncthreads();                          // B2: sred ready, sp reads done
    float woff = 0.f;
    #pragma unroll
    for (int w = 0; w < 4; ++w) if (w < wave) woff += sred[w];
    const float totY  = sred[0] + sred[1] + sred[2] + sred[3];
    const float totY2 = sred[4] + sred[5] + sred[6] + sred[7];
    const float mean  = totY * (1.f / (float)L);
    const float var   = (totY2 - totY * mean) * (1.f / (float)(L - 1));
    const float s     = fsqrt(var) + EPS;     // std + eps
    const float epsS  = EPS * s;              // r = u / (sqrt(MV(u^2)) + eps*s)

    // ---- 3. exclusive raw-y prefix -> sp ----
    {
        float run = woff + iy - cy;           // exclusive prefix at chunk start
        if (active) {
            #pragma unroll
            for (int j = 0; j < CH; ++j) { sp[base + j] = run; run += y[j]; }
            if (tid == NCHUNK - 1) sp[L] = run;
        }
    }
    __syncthreads();                          // B3: y-prefix ready

    // ---- 4. pass B: u = y - MA_sum(y)/251 (z-norm cancels in interior) ----
    const float inv251 = 1.f / 251.f;
    float cu = 0.f;
    if (active) {
        if (tid >= 9 && tid <= 240) {         // untruncated windows, no mean
            #pragma unroll
            for (int j = 0; j < CH; ++j) {
                const int i = base + j;
                const float sumY = sp[i + 126] - sp[i - 125];
                const float u = fmaf(sumY, -inv251, y[j]);
                y[j] = u;
                cu   = fmaf(u, u, cu);
            }
        } else {                              // clamped: mean correction
            #pragma unroll
            for (int j = 0; j < CH; ++j) {
                const int i  = base + j;
                const int lo = (i > 125) ? i - 125 : 0;
                const int hi = (i + 126 < L) ? i + 126 : L;
                const float sumY = sp[hi] - sp[lo];
                const float cnt  = (float)(hi - lo);
                // u = y - m*(1 - cnt/251) - sumY/251
                float u = y[j] - mean * (1.f - cnt * inv251);
                u = fmaf(sumY, -inv251, u);
                y[j] = u;
                cu   = fmaf(u, u, cu);
            }
        }
    }
    float iu = cu;
    #pragma unroll
    for (int d = 1; d < 64; d <<= 1) {
        const float u = __shfl_up(iu, (unsigned)d, 64);
        if (lane >= d) iu += u;
    }
    if (lane == 63) sred[wave] = iu;          // safe: sred(A) last read before B3
    __syncthreads();                          // B4: window reads done, sred(B) ready
    float woff2 = 0.f;
    #pragma unroll
    for (int w = 0; w < 4; ++w) if (w < wave) woff2 += sred[w];

    // ---- 5. exclusive u^2-prefix -> sp ----
    {
        float run = woff2 + iu - cu;
        if (active) {
            #pragma unroll
            for (int j = 0; j < CH; ++j) { sp[base + j] = run; run = fmaf(y[j], y[j], run); }
            if (tid == NCHUNK - 1) sp[L] = run;
        }
    }
    __syncthreads();                          // B5: u^2-prefix ready

    // ---- 6. epilogue: r = u / (sqrt(MV)+eps*s), in registers ----
    const float inv501 = 1.f / 501.f;
    if (active) {
        if (tid >= 17 && tid <= 232) {        // untruncated MV windows
            #pragma unroll
            for (int j = 0; j < CH; ++j) {
                const int i = base + j;
                float W = (sp[i + 251] - sp[i - 250]) * inv501;
                W = fmaxf(W, 0.f);
                y[j] = y[j] * frcp(fsqrt(W) + epsS);
            }
        } else {                              // clamped
            #pragma unroll
            for (int j = 0; j < CH; ++j) {
                const int i  = base + j;
                const int lo = (i > 250) ? i - 250 : 0;
                const int hi = (i + 251 < L) ? i + 251 : L;
                float W = (sp[hi] - sp[lo]) * inv501;
                W = fmaxf(W, 0.f);
                y[j] = y[j] * frcp(fsqrt(W) + epsS);
            }
        }
    }
    __syncthreads();                          // B6: all prefix reads done

    // ---- 7. bounce r through sp (chunk layout == linear) ----
    if (active) {
        #pragma unroll
        for (int j = 0; j < CH; ++j) sp[base + j] = y[j];
    }
    __syncthreads();                          // B7: result staged

    // ---- 8. coalesced store ----
    {
        const float2* sp2 = reinterpret_cast<const float2*>(sp);
        float2* rout2 = reinterpret_cast<float2*>(rout);
        for (int i = tid; i < NPAIR; i += BLK) rout2[i] = sp2[i];
    }
}

}  // namespace

extern "C" void kernel_launch(void* const* d_in, const int* in_sizes, int n_in,
                              void* d_out, int out_size, void* d_ws, size_t ws_size,
                              hipStream_t stream) {
    const float* x = (const float*)d_in[0];
    float* out = (float*)d_out;
    const int rows = in_sizes[0] / L;   // 8192
    preproc_kernel<<<rows, BLK, 0, stream>>>(x, out);
}